// Round 1
// baseline (8904.907 us; speedup 1.0000x reference)
//
#include <hip/hip_runtime.h>
#include <math.h>

// Problem constants (match reference)
#define NN 50000
#define KN 16
// ws layout in floats:
//  qx [50000*128] @ 0           (x@Wq_top + qconst, pre-scaled by 1/sqrt(128))
//  kx [50000*128] @ 6400000     (x@Wk_top)
//  vo [50000*128] @ 12800000    (x@(Wv_top@Wo))
//  Wvo_top [128*128] @ 19200000 (Wv_top@Wo)
//  Wvo_bot [64*128]  @ 19216384 (Wv_bot@Wo)
//  qconst  [128]     @ 19224576 (time2vec(0)@Wq_bot)
#define QX 0
#define KX 6400000
#define VO 12800000
#define WVOT 19200000
#define WVOB 19216384
#define QC 19224576

// ---------------- prep: tiny folded-weight GEMMs ----------------
__global__ __launch_bounds__(128) void tgat_prep(
    const float* __restrict__ Wq, const float* __restrict__ Wv,
    const float* __restrict__ Wo, const float* __restrict__ t2v_b0,
    const float* __restrict__ t2v_B, float* __restrict__ ws) {
  const int h = threadIdx.x;
  const int b = blockIdx.x;
  if (b < 192) {
    // Wvo row b = Wv[b,:] @ Wo   (rows 0..127 = top, 128..191 = bot)
    const float* wvrow = Wv + b * 128;
    float acc = 0.f;
#pragma unroll 8
    for (int f = 0; f < 128; ++f) acc += wvrow[f] * Wo[f * 128 + h];
    if (b < 128) ws[WVOT + b * 128 + h] = acc;
    else         ws[WVOB + (b - 128) * 128 + h] = acc;
  } else {
    // qconst = time2vec(0) @ Wq_bot ; time2vec(0) = [b0, sin(B_j)]
    float acc = t2v_b0[0] * Wq[128 * 128 + h];
    for (int j = 1; j < 64; ++j)
      acc += sinf(t2v_B[j - 1]) * Wq[(128 + j) * 128 + h];
    ws[QC + h] = acc;
  }
}

// ---------------- precompute: qx / kx / vo = x @ W (weights in VGPRs) ----------------
__global__ __launch_bounds__(128) void tgat_precomp(
    const float* __restrict__ x, const float* __restrict__ Wq,
    const float* __restrict__ Wk, float* __restrict__ ws) {
  const int h = threadIdx.x;
  const int y = blockIdx.y;             // 0:q 1:k 2:vo
  const int n0 = blockIdx.x * 128;      // 128 nodes per block
  const float* Wsel = (y == 0) ? Wq : (y == 1) ? Wk : (ws + WVOT);

  float w[128];
#pragma unroll
  for (int f = 0; f < 128; ++f) w[f] = Wsel[f * 128 + h];
  float qc = (y == 0) ? ws[QC + h] : 0.f;
  float* outp = ws + ((y == 0) ? QX : (y == 1) ? KX : VO);

  __shared__ float4 sh[8 * 32];  // 8 staged x rows
  for (int c = 0; c < 16; ++c) {
    const int nb = n0 + c * 8;
    __syncthreads();
#pragma unroll
    for (int r = 0; r < 8; ++r) {
      const int n = nb + r;
      ((float*)sh)[r * 128 + h] = (n < NN) ? x[(size_t)n * 128 + h] : 0.f;
    }
    __syncthreads();
#pragma unroll
    for (int r = 0; r < 8; ++r) {
      const int n = nb + r;
      if (n < NN) {
        float acc = 0.f;
#pragma unroll
        for (int f4 = 0; f4 < 32; ++f4) {
          const float4 xv = sh[r * 32 + f4];  // wave-uniform broadcast read
          acc += xv.x * w[f4 * 4 + 0];
          acc += xv.y * w[f4 * 4 + 1];
          acc += xv.z * w[f4 * 4 + 2];
          acc += xv.w * w[f4 * 4 + 3];
        }
        if (y == 0) acc = (acc + qc) * 0.08838834764831845f;  // 1/sqrt(128)
        outp[(size_t)n * 128 + h] = acc;
      }
    }
  }
}

// ---------------- main: per-node attention over 16 neighbors ----------------
__global__ __launch_bounds__(128) void tgat_main(
    const float* __restrict__ ts, const int* __restrict__ idx,
    const float* __restrict__ t2v_w0, const float* __restrict__ t2v_b0,
    const float* __restrict__ t2v_W, const float* __restrict__ t2v_B,
    const float* __restrict__ Wk, const float* __restrict__ bo,
    const float* __restrict__ ws, float* __restrict__ out) {
  const int t = threadIdx.x;     // = output feature h
  const int lane = t & 63;
  const int wid = t >> 6;

  __shared__ float ts_s[16];
  __shared__ int   idx_s[16];
  __shared__ float te_s[16 * 64];
  __shared__ float spart[2][16];

  // weight columns in registers: Wk_bot[:,h] and Wvo_bot[:,h]
  float wk[64], wvo[64];
#pragma unroll
  for (int j = 0; j < 64; ++j) wk[j]  = Wk[(size_t)(128 + j) * 128 + t];
#pragma unroll
  for (int j = 0; j < 64; ++j) wvo[j] = ws[WVOB + j * 128 + t];

  const float w0 = t2v_w0[0], b0 = t2v_b0[0];
  const float bo_h = bo[t];
  const float* qx = ws + QX;
  const float* kx = ws + KX;
  const float* vo = ws + VO;

  const int n0 = blockIdx.x * 16;
  for (int ni = 0; ni < 16; ++ni) {
    const int n = n0 + ni;
    __syncthreads();
    if (t < 16) { ts_s[t] = ts[n * 16 + t]; idx_s[t] = idx[n * 16 + t]; }
    __syncthreads();
    // time2vec for all 16 neighbors -> LDS (8 values per thread)
#pragma unroll
    for (int r = 0; r < 8; ++r) {
      const int id = r * 128 + t;
      const int k = id >> 6, j = id & 63;
      const float tv = ts_s[k];
      te_s[id] = (j == 0) ? (tv * w0 + b0)
                          : sinf(tv * t2v_W[j - 1] + t2v_B[j - 1]);
    }
    __syncthreads();

    const float qh = qx[(size_t)n * 128 + t];
    float vreg[16];
    int ia = idx_s[0];
    float ka = kx[(size_t)ia * 128 + t];
    float va = vo[(size_t)ia * 128 + t];
#pragma unroll
    for (int k = 0; k < 16; ++k) {
      float kb = 0.f, vb = 0.f;
      if (k < 15) {  // prefetch next neighbor's gather
        const int ib = idx_s[k + 1];
        kb = kx[(size_t)ib * 128 + t];
        vb = vo[(size_t)ib * 128 + t];
      }
      float kacc = ka, vacc = va;
      const float4* te4 = (const float4*)(te_s + k * 64);
#pragma unroll
      for (int j4 = 0; j4 < 16; ++j4) {
        const float4 t4 = te4[j4];  // wave-uniform broadcast
        kacc += t4.x * wk[j4 * 4 + 0];  vacc += t4.x * wvo[j4 * 4 + 0];
        kacc += t4.y * wk[j4 * 4 + 1];  vacc += t4.y * wvo[j4 * 4 + 1];
        kacc += t4.z * wk[j4 * 4 + 2];  vacc += t4.z * wvo[j4 * 4 + 2];
        kacc += t4.w * wk[j4 * 4 + 3];  vacc += t4.w * wvo[j4 * 4 + 3];
      }
      float p = qh * kacc;  // qh pre-scaled by 1/sqrt(128)
#pragma unroll
      for (int d = 1; d < 64; d <<= 1) p += __shfl_xor(p, d, 64);
      if (lane == 0) spart[wid][k] = p;
      vreg[k] = vacc;
      ka = kb; va = vb;
    }
    __syncthreads();

    // softmax over 16 scores (redundant per thread; LDS broadcast reads)
    float m = -1e30f;
#pragma unroll
    for (int k = 0; k < 16; ++k) m = fmaxf(m, spart[0][k] + spart[1][k]);
    float ek[16], sum = 0.f;
#pragma unroll
    for (int k = 0; k < 16; ++k) {
      ek[k] = expf(spart[0][k] + spart[1][k] - m);
      sum += ek[k];
    }
    const float inv = 1.f / sum;
    float acc = 0.f;
#pragma unroll
    for (int k = 0; k < 16; ++k) acc += ek[k] * vreg[k];
    acc = acc * inv + bo_h;         // Wo already folded into vo/wvo
    out[(size_t)n * 128 + t] = fmaxf(acc, 0.f);
  }
}

extern "C" void kernel_launch(void* const* d_in, const int* in_sizes, int n_in,
                              void* d_out, int out_size, void* d_ws, size_t ws_size,
                              hipStream_t stream) {
  const float* x    = (const float*)d_in[0];
  const float* ts   = (const float*)d_in[1];
  const int*   idx  = (const int*)  d_in[2];
  const float* w0   = (const float*)d_in[3];
  const float* b0   = (const float*)d_in[4];
  const float* t2vW = (const float*)d_in[5];
  const float* t2vB = (const float*)d_in[6];
  const float* Wq   = (const float*)d_in[7];
  const float* Wk   = (const float*)d_in[8];
  const float* Wv   = (const float*)d_in[9];
  const float* Wo   = (const float*)d_in[10];
  const float* bo   = (const float*)d_in[11];
  float* ws  = (float*)d_ws;   // needs ~76.9 MB
  float* out = (float*)d_out;

  tgat_prep<<<193, 128, 0, stream>>>(Wq, Wv, Wo, b0, t2vB, ws);
  tgat_precomp<<<dim3(391, 3), 128, 0, stream>>>(x, Wq, Wk, ws);
  tgat_main<<<3125, 128, 0, stream>>>(ts, idx, w0, b0, t2vW, t2vB, Wk, bo, ws, out);
}

// Round 2
// 507.764 us; speedup vs baseline: 17.5375x; 17.5375x over previous
//
#include <hip/hip_runtime.h>
#include <math.h>

#define NN 50000
// ws layout (float offsets)
#define QX   0           // [50000*128] (x@Wq_top + qconst)*s
#define KX   6400000     // [50000*128] x@Wk_top
#define VO   12800000    // [50000*128] x@(Wv_top@Wo)
#define QKX  19200000    // [50000*64]  qk = Wk_bot @ q   (s folded)
#define WVOT 22400000    // [128*128]   Wv_top@Wo
#define WVOB 22416384    // [64*128]    Wv_bot@Wo
#define QC   22424576    // [128]       time2vec(0)@Wq_bot (unscaled)
#define MQK  22424704    // [128*64]    s * Wq_top @ Wk_bot^T
#define CQK  22432896    // [64]        s * Wk_bot @ qconst
#define SCL  0.08838834764831845f   // 1/sqrt(128)

// ---------------- prep: folded-weight mini-GEMMs ----------------
__global__ __launch_bounds__(128) void tgat_prep(
    const float* __restrict__ Wq, const float* __restrict__ Wk,
    const float* __restrict__ Wv, const float* __restrict__ Wo,
    const float* __restrict__ t2v_b0, const float* __restrict__ t2v_B,
    float* __restrict__ ws) {
  const int h = threadIdx.x;
  const int b = blockIdx.x;
  if (b < 192) {
    // Wvo row b = Wv[b,:] @ Wo
    const float* wvrow = Wv + b * 128;
    float acc = 0.f;
#pragma unroll 8
    for (int f = 0; f < 128; ++f) acc += wvrow[f] * Wo[f * 128 + h];
    if (b < 128) ws[WVOT + b * 128 + h] = acc;
    else         ws[WVOB + (b - 128) * 128 + h] = acc;
  } else if (b == 192) {
    // qconst = time2vec(0) @ Wq_bot ; time2vec(0) = [b0, sin(B_j)]
    float acc = t2v_b0[0] * Wq[128 * 128 + h];
    for (int j = 1; j < 64; ++j)
      acc += __sinf(t2v_B[j - 1]) * Wq[(128 + j) * 128 + h];
    ws[QC + h] = acc;
  } else {
    // Mqk[f][j] = s * Wq_top[f,:] . Wk_bot[j,:]
    const int f = b - 193;
    if (h < 64) {
      const float* wqrow = Wq + f * 128;
      const float* wkrow = Wk + (128 + h) * 128;
      float acc = 0.f;
#pragma unroll 8
      for (int i = 0; i < 128; ++i) acc += wqrow[i] * wkrow[i];
      ws[MQK + f * 64 + h] = SCL * acc;
    }
  }
}

// cqk[j] = s * qconst . Wk_bot[j,:]   (needs QC from tgat_prep)
__global__ __launch_bounds__(64) void tgat_prep2(
    const float* __restrict__ Wk, float* __restrict__ ws) {
  const int j = threadIdx.x;
  const float* wkrow = Wk + (128 + j) * 128;
  float acc = 0.f;
#pragma unroll 8
  for (int i = 0; i < 128; ++i) acc += ws[QC + i] * wkrow[i];
  ws[CQK + j] = SCL * acc;
}

// ---------------- precompute tables: qx / kx / vo / qk ----------------
__global__ __launch_bounds__(128) void tgat_precomp(
    const float* __restrict__ x, const float* __restrict__ Wq,
    const float* __restrict__ Wk, float* __restrict__ ws) {
  const int h = threadIdx.x;
  const int y = blockIdx.y;             // 0:q 1:k 2:vo 3:qk
  const int n0 = blockIdx.x * 128;      // 128 nodes per block

  float w[128];
  float addc = 0.f;
  const float* Wsel;
  float* outp;
  if (y == 0)      { Wsel = Wq;        outp = ws + QX; }
  else if (y == 1) { Wsel = Wk;        outp = ws + KX; }
  else if (y == 2) { Wsel = ws + WVOT; outp = ws + VO; }
  else             { Wsel = ws + MQK;  outp = ws + QKX; }

  if (y == 3) {
    if (h < 64) {
#pragma unroll
      for (int f = 0; f < 128; ++f) w[f] = Wsel[f * 64 + h];
      addc = ws[CQK + h];
    }
  } else {
#pragma unroll
    for (int f = 0; f < 128; ++f) w[f] = Wsel[f * 128 + h];
    if (y == 0) addc = ws[QC + h];
  }

  __shared__ float4 sh[8 * 32];  // 8 staged x rows
  for (int c = 0; c < 16; ++c) {
    const int nb = n0 + c * 8;
    __syncthreads();
#pragma unroll
    for (int r = 0; r < 8; ++r) {
      const int n = nb + r;
      ((float*)sh)[r * 128 + h] = (n < NN) ? x[(size_t)n * 128 + h] : 0.f;
    }
    __syncthreads();
    if (y == 3 && h >= 64) continue;
#pragma unroll
    for (int r = 0; r < 8; ++r) {
      const int n = nb + r;
      if (n < NN) {
        float acc = 0.f;
#pragma unroll
        for (int f4 = 0; f4 < 32; ++f4) {
          const float4 xv = sh[r * 32 + f4];  // wave-uniform broadcast read
          acc += xv.x * w[f4 * 4 + 0];
          acc += xv.y * w[f4 * 4 + 1];
          acc += xv.z * w[f4 * 4 + 2];
          acc += xv.w * w[f4 * 4 + 3];
        }
        if (y == 0)      outp[(size_t)n * 128 + h] = (acc + addc) * SCL;
        else if (y == 3) outp[(size_t)n * 64 + h]  = acc + addc;
        else             outp[(size_t)n * 128 + h] = acc;
      }
    }
  }
}

// ---------------- main: per-node attention over 16 neighbors ----------------
__global__ __launch_bounds__(128, 4) void tgat_main(
    const float* __restrict__ ts, const int* __restrict__ idx,
    const float* __restrict__ t2v_w0, const float* __restrict__ t2v_b0,
    const float* __restrict__ t2v_W, const float* __restrict__ t2v_B,
    const float* __restrict__ bo, const float* __restrict__ ws,
    float* __restrict__ out) {
  const int t = threadIdx.x;

  __shared__ float ts_s[16];
  __shared__ int   idx_s[16];
  __shared__ float q_s[128], qk_s[64], te_s[16 * 64], s_s[16], ta_s[64];
  __shared__ float tw_s[64], tb_s[64];

  // Only per-thread persistent weights: Wvo_bot column (64 VGPRs)
  float wvo[64];
#pragma unroll
  for (int j = 0; j < 64; ++j) wvo[j] = ws[WVOB + j * 128 + t];
  const float w0 = t2v_w0[0], b0v = t2v_b0[0];
  const float bo_h = bo[t];
  if (t < 64) {
    tw_s[t] = (t == 0) ? 0.f : t2v_W[t - 1];
    tb_s[t] = (t == 0) ? 0.f : t2v_B[t - 1];
  }

  const float* qx  = ws + QX;
  const float* kx  = ws + KX;
  const float* vo  = ws + VO;
  const float* qkx = ws + QKX;

  const int n0 = blockIdx.x * 16;
  for (int ni = 0; ni < 16; ++ni) {
    const int n = n0 + ni;
    __syncthreads();  // protect LDS from previous iteration's readers
    if (t < 16) { ts_s[t] = ts[n * 16 + t]; idx_s[t] = idx[n * 16 + t]; }
    q_s[t] = qx[(size_t)n * 128 + t];
    if (t < 64) qk_s[t] = qkx[(size_t)n * 64 + t];
    __syncthreads();

    // time2vec for 16 neighbors -> LDS (8 elems/thread)
#pragma unroll
    for (int r = 0; r < 8; ++r) {
      const int id = r * 128 + t;
      const int k = id >> 6, j = id & 63;
      const float tv = ts_s[k];
      te_s[id] = (j == 0) ? (tv * w0 + b0v) : __sinf(tv * tw_s[j] + tb_s[j]);
    }
    __syncthreads();

    // scores: s_k = q . kx[idx_k]  +  te_k . qk     (8 lanes per k)
    {
      const int k = t >> 3, jj = t & 7;
      const float* krow = kx + (size_t)idx_s[k] * 128 + jj * 16;
      const float4* q4 = (const float4*)(q_s + jj * 16);
      float acc = 0.f;
#pragma unroll
      for (int i4 = 0; i4 < 4; ++i4) {
        const float4 kv = ((const float4*)krow)[i4];
        const float4 qv = q4[i4];
        acc += kv.x * qv.x + kv.y * qv.y + kv.z * qv.z + kv.w * qv.w;
      }
      const float* tep = te_s + k * 64 + jj * 8;
      const float* qkp = qk_s + jj * 8;
#pragma unroll
      for (int i = 0; i < 8; ++i) acc += tep[i] * qkp[i];
      acc += __shfl_xor(acc, 1, 64);
      acc += __shfl_xor(acc, 2, 64);
      acc += __shfl_xor(acc, 4, 64);
      if (jj == 0) s_s[k] = acc;
    }
    __syncthreads();

    // softmax over 16 (redundant per thread — cheap)
    float a[16];
    {
      float m = -1e30f;
#pragma unroll
      for (int k = 0; k < 16; ++k) m = fmaxf(m, s_s[k]);
      float sum = 0.f;
#pragma unroll
      for (int k = 0; k < 16; ++k) { a[k] = __expf(s_s[k] - m); sum += a[k]; }
      const float inv = 1.f / sum;
#pragma unroll
      for (int k = 0; k < 16; ++k) a[k] *= inv;
    }
    // tagg[j] = sum_k a_k * te_k[j]
    if (t < 64) {
      float tsum = 0.f;
#pragma unroll
      for (int k = 0; k < 16; ++k) tsum += a[k] * te_s[k * 64 + t];
      ta_s[t] = tsum;
    }
    __syncthreads();

    // out_h = relu( bo_h + sum_k a_k*vo[idx_k][h] + tagg @ Wvo_bot[:,h] )
    {
      float vg[16];
#pragma unroll
      for (int k = 0; k < 16; ++k) vg[k] = vo[(size_t)idx_s[k] * 128 + t];
      float acc = bo_h;
#pragma unroll
      for (int k = 0; k < 16; ++k) acc += a[k] * vg[k];
      const float4* ta4 = (const float4*)ta_s;
#pragma unroll
      for (int j4 = 0; j4 < 16; ++j4) {
        const float4 tv = ta4[j4];
        acc += tv.x * wvo[j4 * 4 + 0] + tv.y * wvo[j4 * 4 + 1]
             + tv.z * wvo[j4 * 4 + 2] + tv.w * wvo[j4 * 4 + 3];
      }
      out[(size_t)n * 128 + t] = fmaxf(acc, 0.f);
    }
  }
}

extern "C" void kernel_launch(void* const* d_in, const int* in_sizes, int n_in,
                              void* d_out, int out_size, void* d_ws, size_t ws_size,
                              hipStream_t stream) {
  const float* x    = (const float*)d_in[0];
  const float* ts   = (const float*)d_in[1];
  const int*   idx  = (const int*)  d_in[2];
  const float* w0   = (const float*)d_in[3];
  const float* b0   = (const float*)d_in[4];
  const float* t2vW = (const float*)d_in[5];
  const float* t2vB = (const float*)d_in[6];
  const float* Wq   = (const float*)d_in[7];
  const float* Wk   = (const float*)d_in[8];
  const float* Wv   = (const float*)d_in[9];
  const float* Wo   = (const float*)d_in[10];
  const float* bo   = (const float*)d_in[11];
  float* ws  = (float*)d_ws;   // needs ~89.8 MB
  float* out = (float*)d_out;

  tgat_prep<<<321, 128, 0, stream>>>(Wq, Wk, Wv, Wo, b0, t2vB, ws);
  tgat_prep2<<<1, 64, 0, stream>>>(Wk, ws);
  tgat_precomp<<<dim3(391, 4), 128, 0, stream>>>(x, Wq, Wk, ws);
  tgat_main<<<3125, 128, 0, stream>>>(ts, idx, w0, b0, t2vW, t2vB, bo, ws, out);
}

// Round 3
// 452.280 us; speedup vs baseline: 19.6889x; 1.1227x over previous
//
#include <hip/hip_runtime.h>
#include <math.h>

#define NN 50000
#define SCL 0.08838834764831845f   // 1/sqrt(128)

// ---- ws layout ----
// fp32 region (float offsets from ws base)
#define QX    0          // [50000*128] (x@Wq_top + qconst)*SCL
#define QKX   6400000    // [50000*64]  x@Mqk + cqk
#define WVOT  9600000    // [128*128]   Wv_top@Wo
#define WVOB  9616384    // [64*128]    Wv_bot@Wo
#define QC    9624576    // [128]       time2vec(0)@Wq_bot
#define MQK   9624704    // [128*64]    SCL * Wq_top @ Wk_bot^T
#define CQK   9632896    // [64]        SCL * Wk_bot @ qconst
#define UBASE 9632960    // ushort region starts here (float offset, 16B-aligned)
// ushort offsets within ubase
#define KXB   0          // [50000*128] bf16 x@Wk_top
#define VOB   6400000    // [50000*128] bf16 x@(Wv_top@Wo)
#define XB    12800000   // [50000*128] bf16 x
#define WCAT  19200000   // [448][128]  bf16 weight block, [col][k] (transposed)

typedef __attribute__((ext_vector_type(8))) short bf16x8;
typedef __attribute__((ext_vector_type(4))) float f32x4;

__device__ __forceinline__ float bf2f(unsigned short u) {
  union { unsigned int i; float f; } v; v.i = ((unsigned int)u) << 16; return v.f;
}
__device__ __forceinline__ unsigned short f2bf(float f) {
  union { float f; unsigned int i; } v; v.f = f;
  return (unsigned short)((v.i + 0x7fff + ((v.i >> 16) & 1)) >> 16);  // RNE
}

// ---------------- cast x -> bf16 table ----------------
__global__ __launch_bounds__(256) void tgat_xcast(
    const float* __restrict__ x, unsigned short* __restrict__ xb) {
  const int i = blockIdx.x * 256 + threadIdx.x;   // float4 index, 1.6M total
  const float4 v = ((const float4*)x)[i];
  union { unsigned short u[4]; unsigned long long ll; } o;
  o.u[0] = f2bf(v.x); o.u[1] = f2bf(v.y); o.u[2] = f2bf(v.z); o.u[3] = f2bf(v.w);
  ((unsigned long long*)xb)[i] = o.ll;
}

// ---------------- prep1: folded-weight mini-GEMMs (fp32) ----------------
__global__ __launch_bounds__(128) void tgat_prep(
    const float* __restrict__ Wq, const float* __restrict__ Wk,
    const float* __restrict__ Wv, const float* __restrict__ Wo,
    const float* __restrict__ t2v_b0, const float* __restrict__ t2v_B,
    float* __restrict__ ws) {
  const int h = threadIdx.x;
  const int b = blockIdx.x;
  if (b < 192) {
    const float* wvrow = Wv + b * 128;       // Wvo row b = Wv[b,:] @ Wo
    float acc = 0.f;
#pragma unroll 8
    for (int f = 0; f < 128; ++f) acc += wvrow[f] * Wo[f * 128 + h];
    if (b < 128) ws[WVOT + b * 128 + h] = acc;
    else         ws[WVOB + (b - 128) * 128 + h] = acc;
  } else if (b == 192) {
    float acc = t2v_b0[0] * Wq[128 * 128 + h];   // time2vec(0)@Wq_bot
    for (int j = 1; j < 64; ++j)
      acc += __sinf(t2v_B[j - 1]) * Wq[(128 + j) * 128 + h];
    ws[QC + h] = acc;
  } else {
    const int f = b - 193;                    // Mqk[f][j] = s*Wq_top[f,:].Wk_bot[j,:]
    if (h < 64) {
      const float* wqrow = Wq + f * 128;
      const float* wkrow = Wk + (128 + h) * 128;
      float acc = 0.f;
#pragma unroll 8
      for (int i = 0; i < 128; ++i) acc += wqrow[i] * wkrow[i];
      ws[MQK + f * 64 + h] = SCL * acc;
    }
  }
}

// ---------------- prep2: cqk + bf16 Wcat [col][k] ----------------
__global__ __launch_bounds__(128) void tgat_prep2(
    const float* __restrict__ Wq, const float* __restrict__ Wk,
    float* __restrict__ ws, unsigned short* __restrict__ ub) {
  const int t = threadIdx.x, b = blockIdx.x;
  if (b < 448) {
    float v;
    if (b < 128)      v = Wq[t * 128 + b];
    else if (b < 256) v = Wk[t * 128 + (b - 128)];
    else if (b < 384) v = ws[WVOT + t * 128 + (b - 256)];
    else              v = ws[MQK + t * 64 + (b - 384)];
    ub[WCAT + b * 128 + t] = f2bf(v);
  } else if (t < 64) {
    const float* wkrow = Wk + (128 + t) * 128;   // cqk = SCL * Wk_bot @ qconst
    float acc = 0.f;
#pragma unroll 8
    for (int i = 0; i < 128; ++i) acc += ws[QC + i] * wkrow[i];
    ws[CQK + t] = SCL * acc;
  }
}

// ---------------- precomp: [50000,128]@[128,448] via MFMA, no LDS ----------------
__global__ __launch_bounds__(64) void tgat_precomp_mfma(
    const unsigned short* __restrict__ ub, float* __restrict__ ws) {
  const int lane = threadIdx.x;
  const int mr = blockIdx.x * 16;        // output rows
  const int c0 = blockIdx.y * 64;        // output cols (uniform table per tile)
  const unsigned short* xb = ub + XB;
  const unsigned short* wc = ub + WCAT;

  const int arow = lane & 15;
  const int ko = (lane >> 4) * 8;

  bf16x8 afr[4];
#pragma unroll
  for (int kk = 0; kk < 4; ++kk)
    afr[kk] = *(const bf16x8*)(xb + (size_t)(mr + arow) * 128 + kk * 32 + ko);

  bf16x8 bfr[4][4];
#pragma unroll
  for (int ct = 0; ct < 4; ++ct) {
    const int col = c0 + ct * 16 + (lane & 15);
#pragma unroll
    for (int kk = 0; kk < 4; ++kk)
      bfr[ct][kk] = *(const bf16x8*)(wc + (size_t)col * 128 + kk * 32 + ko);
  }

  f32x4 acc[4] = {{0.f, 0.f, 0.f, 0.f}, {0.f, 0.f, 0.f, 0.f},
                  {0.f, 0.f, 0.f, 0.f}, {0.f, 0.f, 0.f, 0.f}};
#pragma unroll
  for (int ct = 0; ct < 4; ++ct)
#pragma unroll
    for (int kk = 0; kk < 4; ++kk)
      acc[ct] = __builtin_amdgcn_mfma_f32_16x16x32_bf16(afr[kk], bfr[ct][kk], acc[ct], 0, 0, 0);

  const int cl = lane & 15;
  const int rbase = (lane >> 4) * 4;
  unsigned short* kxb = (unsigned short*)(ws + UBASE) + KXB;
  unsigned short* vob = (unsigned short*)(ws + UBASE) + VOB;
#pragma unroll
  for (int ct = 0; ct < 4; ++ct) {
    const int gc = c0 + ct * 16 + cl;
#pragma unroll
    for (int r = 0; r < 4; ++r) {
      const size_t n = mr + rbase + r;
      const float v = acc[ct][r];
      if (gc < 128)        ws[QX + n * 128 + gc] = (v + ws[QC + gc]) * SCL;
      else if (gc < 256)   kxb[n * 128 + (gc - 128)] = f2bf(v);
      else if (gc < 384)   vob[n * 128 + (gc - 256)] = f2bf(v);
      else                 ws[QKX + n * 64 + (gc - 384)] = v + ws[CQK + gc - 384];
    }
  }
}

// ---------------- main: per-node attention over 16 neighbors ----------------
__global__ __launch_bounds__(128, 4) void tgat_main(
    const float* __restrict__ ts, const int* __restrict__ idx,
    const float* __restrict__ t2v_w0, const float* __restrict__ t2v_b0,
    const float* __restrict__ t2v_W, const float* __restrict__ t2v_B,
    const float* __restrict__ bo, const float* __restrict__ ws,
    float* __restrict__ out) {
  const int t = threadIdx.x;

  __shared__ float ts_s[16];
  __shared__ int   idx_s[16];
  __shared__ float q_s[128], qk_s[64], te_s[16 * 66], s_s[16], ta_s[64];
  __shared__ float tw_s[64], tb_s[64];

  float wvo[64];                       // Wvo_bot column (fp32)
#pragma unroll
  for (int j = 0; j < 64; ++j) wvo[j] = ws[WVOB + j * 128 + t];
  const float w0 = t2v_w0[0], b0v = t2v_b0[0];
  const float bo_h = bo[t];
  if (t < 64) {
    tw_s[t] = (t == 0) ? 0.f : t2v_W[t - 1];
    tb_s[t] = (t == 0) ? 0.f : t2v_B[t - 1];
  }

  const float* qx  = ws + QX;
  const float* qkx = ws + QKX;
  const unsigned short* kxb = (const unsigned short*)(ws + UBASE) + KXB;
  const unsigned short* vob = (const unsigned short*)(ws + UBASE) + VOB;

  const int n0 = blockIdx.x * 16;
  for (int ni = 0; ni < 16; ++ni) {
    const int n = n0 + ni;
    __syncthreads();
    if (t < 16) { ts_s[t] = ts[n * 16 + t]; idx_s[t] = idx[n * 16 + t]; }
    q_s[t] = qx[(size_t)n * 128 + t];
    if (t < 64) qk_s[t] = qkx[(size_t)n * 64 + t];
    __syncthreads();

    // time2vec for 16 neighbors -> LDS, rows padded to 66 (bank spread)
#pragma unroll
    for (int r = 0; r < 8; ++r) {
      const int id = r * 128 + t;
      const int k = id >> 6, j = id & 63;
      const float tv = ts_s[k];
      te_s[k * 66 + j] = (j == 0) ? (tv * w0 + b0v) : __sinf(tv * tw_s[j] + tb_s[j]);
    }
    __syncthreads();

    // scores: s_k = q . kx[idx_k] + te_k . qk   (8 lanes per k)
    {
      const int k = t >> 3, jj = t & 7;
      const unsigned short* krow = kxb + (size_t)idx_s[k] * 128 + jj * 16;
      float acc = 0.f;
#pragma unroll
      for (int half = 0; half < 2; ++half) {
        const bf16x8 kv = *(const bf16x8*)(krow + half * 8);
        const float* qp = q_s + jj * 16 + half * 8;
#pragma unroll
        for (int i = 0; i < 8; ++i)
          acc += bf2f((unsigned short)kv[i]) * qp[i];
      }
      const float* tep = te_s + k * 66 + jj * 8;
      const float* qkp = qk_s + jj * 8;
#pragma unroll
      for (int i = 0; i < 8; ++i) acc += tep[i] * qkp[i];
      acc += __shfl_xor(acc, 1, 64);
      acc += __shfl_xor(acc, 2, 64);
      acc += __shfl_xor(acc, 4, 64);
      if (jj == 0) s_s[k] = acc;
    }

    // prefetch vo gathers (independent of softmax) — hide L3 latency
    unsigned short vg[16];
#pragma unroll
    for (int k = 0; k < 16; ++k) vg[k] = vob[(size_t)idx_s[k] * 128 + t];
    __syncthreads();

    // softmax over 16 (redundant per thread — cheap)
    float a[16];
    {
      float m = -1e30f;
#pragma unroll
      for (int k = 0; k < 16; ++k) m = fmaxf(m, s_s[k]);
      float sum = 0.f;
#pragma unroll
      for (int k = 0; k < 16; ++k) { a[k] = __expf(s_s[k] - m); sum += a[k]; }
      const float inv = 1.f / sum;
#pragma unroll
      for (int k = 0; k < 16; ++k) a[k] *= inv;
    }
    // tagg[j] = sum_k a_k * te_k[j]
    if (t < 64) {
      float tsum = 0.f;
#pragma unroll
      for (int k = 0; k < 16; ++k) tsum += a[k] * te_s[k * 66 + t];
      ta_s[t] = tsum;
    }
    __syncthreads();

    // out_h = relu( bo_h + sum_k a_k*vo[idx_k][h] + tagg @ Wvo_bot[:,h] )
    {
      float acc = bo_h;
#pragma unroll
      for (int k = 0; k < 16; ++k) acc += a[k] * bf2f(vg[k]);
      const float4* ta4 = (const float4*)ta_s;
#pragma unroll
      for (int j4 = 0; j4 < 16; ++j4) {
        const float4 tv = ta4[j4];
        acc += tv.x * wvo[j4 * 4 + 0] + tv.y * wvo[j4 * 4 + 1]
             + tv.z * wvo[j4 * 4 + 2] + tv.w * wvo[j4 * 4 + 3];
      }
      out[(size_t)n * 128 + t] = fmaxf(acc, 0.f);
    }
  }
}

extern "C" void kernel_launch(void* const* d_in, const int* in_sizes, int n_in,
                              void* d_out, int out_size, void* d_ws, size_t ws_size,
                              hipStream_t stream) {
  const float* x    = (const float*)d_in[0];
  const float* ts   = (const float*)d_in[1];
  const int*   idx  = (const int*)  d_in[2];
  const float* w0   = (const float*)d_in[3];
  const float* b0   = (const float*)d_in[4];
  const float* t2vW = (const float*)d_in[5];
  const float* t2vB = (const float*)d_in[6];
  const float* Wq   = (const float*)d_in[7];
  const float* Wk   = (const float*)d_in[8];
  const float* Wv   = (const float*)d_in[9];
  const float* Wo   = (const float*)d_in[10];
  const float* bo   = (const float*)d_in[11];
  float* ws = (float*)d_ws;                      // ~77 MB used
  unsigned short* ub = (unsigned short*)(ws + UBASE);
  float* out = (float*)d_out;

  tgat_xcast<<<6250, 256, 0, stream>>>(x, ub + XB);
  tgat_prep<<<321, 128, 0, stream>>>(Wq, Wk, Wv, Wo, b0, t2vB, ws);
  tgat_prep2<<<449, 128, 0, stream>>>(Wq, Wk, ws, ub);
  tgat_precomp_mfma<<<dim3(3125, 7), 64, 0, stream>>>(ub, ws);
  tgat_main<<<3125, 128, 0, stream>>>(ts, idx, w0, b0, t2vW, t2vB, bo, ws, out);
}

// Round 5
// 297.549 us; speedup vs baseline: 29.9276x; 1.5200x over previous
//
#include <hip/hip_runtime.h>
#include <math.h>

#define NN 50000
#define SCL 0.08838834764831845f   // 1/sqrt(128)

// ---- ws layout (float offsets) ----
#define QX    0          // [50000*128] q table; overwritten by `partial` in main
#define QKX   6400000    // [50000*64]  qk table; first half overwritten by bf16 tagg
#define WVOT  9600000    // [128*128]   Wv_top@Wo
#define WVOB  9616384    // [64*128]    Wv_bot@Wo (f32)
#define QC    9624576    // [128]       time2vec(0)@Wq_bot
#define MQK   9624704    // [128*64]    SCL * Wq_top @ Wk_bot^T
#define CQK   9632896    // [64]        SCL * Wk_bot @ qconst
#define WT    9632960    // [64]        [w0, W...]
#define BT    9633024    // [64]        [b0, B...]
#define UBASE 9633088    // ushort region base (16B aligned)
// ushort offsets within ub
#define KXB   0          // [50000*128] bf16 x@Wk_top
#define VOB   6400000    // [50000*128] bf16 x@(Wv_top@Wo)
#define XB    12800000   // [50000*128] bf16 x
#define WCAT  19200000   // [448][128]  bf16 weights [col][k]
#define WVOBT 19257344   // [128][64]   bf16 Wvo_bot^T [h][j]

typedef __attribute__((ext_vector_type(8))) short bf16x8;
typedef __attribute__((ext_vector_type(4))) float f32x4;

__device__ __forceinline__ float bfl(unsigned int u) {   // low bf16 -> f32
  union { unsigned int i; float f; } v; v.i = u << 16; return v.f;
}
__device__ __forceinline__ float bfh(unsigned int u) {   // high bf16 -> f32
  union { unsigned int i; float f; } v; v.i = u & 0xffff0000u; return v.f;
}
__device__ __forceinline__ unsigned short f2bf(float f) {
  union { float f; unsigned int i; } v; v.f = f;
  return (unsigned short)((v.i + 0x7fff + ((v.i >> 16) & 1)) >> 16);  // RNE
}

// ---------------- cast x -> bf16 ----------------
__global__ __launch_bounds__(256) void tgat_xcast(
    const float* __restrict__ x, unsigned short* __restrict__ xb) {
  const int i = blockIdx.x * 256 + threadIdx.x;
  const float4 v = ((const float4*)x)[i];
  union { unsigned short u[4]; unsigned long long ll; } o;
  o.u[0] = f2bf(v.x); o.u[1] = f2bf(v.y); o.u[2] = f2bf(v.z); o.u[3] = f2bf(v.w);
  ((unsigned long long*)xb)[i] = o.ll;
}

// ---------------- prep1: folded-weight mini-GEMMs ----------------
__global__ __launch_bounds__(128) void tgat_prep(
    const float* __restrict__ Wq, const float* __restrict__ Wk,
    const float* __restrict__ Wv, const float* __restrict__ Wo,
    const float* __restrict__ t2v_b0, const float* __restrict__ t2v_B,
    float* __restrict__ ws) {
  const int h = threadIdx.x;
  const int b = blockIdx.x;
  if (b < 192) {
    const float* wvrow = Wv + b * 128;
    float acc = 0.f;
#pragma unroll 8
    for (int f = 0; f < 128; ++f) acc += wvrow[f] * Wo[f * 128 + h];
    if (b < 128) ws[WVOT + b * 128 + h] = acc;
    else         ws[WVOB + (b - 128) * 128 + h] = acc;
  } else if (b == 192) {
    float acc = t2v_b0[0] * Wq[128 * 128 + h];
    for (int j = 1; j < 64; ++j)
      acc += __sinf(t2v_B[j - 1]) * Wq[(128 + j) * 128 + h];
    ws[QC + h] = acc;
  } else {
    const int f = b - 193;
    if (h < 64) {
      const float* wqrow = Wq + f * 128;
      const float* wkrow = Wk + (128 + h) * 128;
      float acc = 0.f;
#pragma unroll 8
      for (int i = 0; i < 128; ++i) acc += wqrow[i] * wkrow[i];
      ws[MQK + f * 64 + h] = SCL * acc;
    }
  }
}

// ---------------- prep2: WCAT, cqk, wt/bt tables, Wvo_bot^T bf16 ----------------
__global__ __launch_bounds__(128) void tgat_prep2(
    const float* __restrict__ Wq, const float* __restrict__ Wk,
    const float* __restrict__ t2v_w0, const float* __restrict__ t2v_b0,
    const float* __restrict__ t2v_W, const float* __restrict__ t2v_B,
    float* __restrict__ ws, unsigned short* __restrict__ ub) {
  const int t = threadIdx.x, b = blockIdx.x;
  if (b < 448) {
    float v;
    if (b < 128)      v = Wq[t * 128 + b];
    else if (b < 256) v = Wk[t * 128 + (b - 128)];
    else if (b < 384) v = ws[WVOT + t * 128 + (b - 256)];
    else              v = ws[MQK + t * 64 + (b - 384)];
    ub[WCAT + b * 128 + t] = f2bf(v);
  } else if (b == 448) {
    if (t < 64) {
      const float* wkrow = Wk + (128 + t) * 128;
      float acc = 0.f;
#pragma unroll 8
      for (int i = 0; i < 128; ++i) acc += ws[QC + i] * wkrow[i];
      ws[CQK + t] = SCL * acc;
    }
  } else if (b == 449) {
    if (t < 64) {
      ws[WT + t] = (t == 0) ? t2v_w0[0] : t2v_W[t - 1];
      ws[BT + t] = (t == 0) ? t2v_b0[0] : t2v_B[t - 1];
    }
  } else {
    const int h = b - 450;           // 0..127
    if (t < 64) ub[WVOBT + h * 64 + t] = f2bf(ws[WVOB + t * 128 + h]);
  }
}

// ---------------- precomp: [50000,128]@[128,448] via MFMA ----------------
__global__ __launch_bounds__(64) void tgat_precomp_mfma(
    const unsigned short* __restrict__ ub, float* __restrict__ ws) {
  const int lane = threadIdx.x;
  const int mr = blockIdx.x * 16;
  const int c0 = blockIdx.y * 64;
  const unsigned short* xb = ub + XB;
  const unsigned short* wc = ub + WCAT;
  const int arow = lane & 15;
  const int ko = (lane >> 4) * 8;

  bf16x8 afr[4];
#pragma unroll
  for (int kk = 0; kk < 4; ++kk)
    afr[kk] = *(const bf16x8*)(xb + (size_t)(mr + arow) * 128 + kk * 32 + ko);
  bf16x8 bfr[4][4];
#pragma unroll
  for (int ct = 0; ct < 4; ++ct) {
    const int col = c0 + ct * 16 + arow;
#pragma unroll
    for (int kk = 0; kk < 4; ++kk)
      bfr[ct][kk] = *(const bf16x8*)(wc + (size_t)col * 128 + kk * 32 + ko);
  }
  f32x4 acc[4] = {{0,0,0,0},{0,0,0,0},{0,0,0,0},{0,0,0,0}};
#pragma unroll
  for (int ct = 0; ct < 4; ++ct)
#pragma unroll
    for (int kk = 0; kk < 4; ++kk)
      acc[ct] = __builtin_amdgcn_mfma_f32_16x16x32_bf16(afr[kk], bfr[ct][kk], acc[ct], 0, 0, 0);

  const int cl = lane & 15;
  const int rbase = (lane >> 4) * 4;
  unsigned short* kxb = (unsigned short*)(ws + UBASE) + KXB;
  unsigned short* vob = (unsigned short*)(ws + UBASE) + VOB;
#pragma unroll
  for (int ct = 0; ct < 4; ++ct) {
    const int gc = c0 + ct * 16 + cl;
#pragma unroll
    for (int r = 0; r < 4; ++r) {
      const size_t n = mr + rbase + r;
      const float v = acc[ct][r];
      if (gc < 128)        ws[QX + n * 128 + gc] = (v + ws[QC + gc]) * SCL;
      else if (gc < 256)   kxb[n * 128 + (gc - 128)] = f2bf(v);
      else if (gc < 384)   vob[n * 128 + (gc - 256)] = f2bf(v);
      else                 ws[QKX + n * 64 + (gc - 384)] = v + ws[CQK + gc - 384];
    }
  }
}

// ---------------- main: one wave per node, barrier-free ----------------
__global__ __launch_bounds__(256) void tgat_main(
    const float* __restrict__ ts, const int* __restrict__ idx,
    float* ws) {
  const int lane = threadIdx.x & 63;
  const int wv   = threadIdx.x >> 6;
  const int my_k = lane >> 2, my_c = lane & 3;

  __shared__ float lds[4 * 1120];
  float* te_s = lds + wv * 1120;        // [64 j][17] (col = k, pad)
  float* s_s  = te_s + 1088;            // [16]

  const float* qx  = ws + QX;
  const float* qkx = ws + QKX;
  const unsigned short* kxb = (const unsigned short*)(ws + UBASE) + KXB;
  const unsigned short* vob = (const unsigned short*)(ws + UBASE) + VOB;
  float* partial = ws + QX;                              // overlay
  unsigned short* tagg = (unsigned short*)(ws + QKX);    // overlay, row stride 128 ushorts

  // time2vec coeffs for this lane's score slice: j = my_c*16 + i
  float wtc[16], btc[16];
  {
    const float4* w4 = (const float4*)(ws + WT + my_c * 16);
    const float4* b4 = (const float4*)(ws + BT + my_c * 16);
#pragma unroll
    for (int i4 = 0; i4 < 4; ++i4) {
      const float4 a = w4[i4], b = b4[i4];
      wtc[i4*4+0]=a.x; wtc[i4*4+1]=a.y; wtc[i4*4+2]=a.z; wtc[i4*4+3]=a.w;
      btc[i4*4+0]=b.x; btc[i4*4+1]=b.y; btc[i4*4+2]=b.z; btc[i4*4+3]=b.w;
    }
  }

  for (int it = 0; it < 4; ++it) {
    const int n = blockIdx.x * 16 + wv * 4 + it;
    // ---- issue all memory first ----
    const int   iv = idx[n * 16 + (lane & 15)];
    const float tv = ts[n * 16 + (lane & 15)];
    const int i_myk = __shfl(iv, my_k, 64);
    const unsigned short* kr = kxb + (size_t)i_myk * 128 + my_c * 32;
    uint4 kxa = *(const uint4*)(kr);
    uint4 kxbq = *(const uint4*)(kr + 8);
    uint4 kxc = *(const uint4*)(kr + 16);
    uint4 kxd = *(const uint4*)(kr + 24);
    unsigned int vg[16];
#pragma unroll
    for (int k = 0; k < 16; ++k) {
      const int ik = __shfl(iv, k, 64);
      vg[k] = ((const unsigned int*)(vob + (size_t)ik * 128))[lane];
    }
    float4 qa[8];
    {
      const float4* qrow = (const float4*)(qx + (size_t)n * 128 + my_c * 32);
#pragma unroll
      for (int i = 0; i < 8; ++i) qa[i] = qrow[i];
    }
    float4 qk4[4];
    {
      const float4* qkrow = (const float4*)(qkx + (size_t)n * 64 + my_c * 16);
#pragma unroll
      for (int i = 0; i < 4; ++i) qk4[i] = qkrow[i];
    }

    // ---- time2vec for my_k, j = my_c*16+i (computed once, shared via LDS) ----
    const float tvk = __shfl(tv, my_k, 64);
    float te[16];
#pragma unroll
    for (int i = 0; i < 16; ++i) te[i] = __sinf(tvk * wtc[i] + btc[i]);
    if (my_c == 0) te[0] = tvk * wtc[0] + btc[0];   // j==0 linear term
#pragma unroll
    for (int i = 0; i < 16; ++i)
      te_s[(my_c * 16 + i) * 17 + my_k] = te[i];

    // ---- score partial: q . kx[idx_k] (32 feats) + te . qk (16 feats) ----
    float p = 0.f;
    {
      const uint4 kk[4] = {kxa, kxbq, kxc, kxd};
#pragma unroll
      for (int q8 = 0; q8 < 4; ++q8) {        // 8 features per uint4
        const float4 qlo = qa[q8 * 2], qhi = qa[q8 * 2 + 1];
        const uint4 u = kk[q8];
        p += bfl(u.x) * qlo.x + bfh(u.x) * qlo.y;
        p += bfl(u.y) * qlo.z + bfh(u.y) * qlo.w;
        p += bfl(u.z) * qhi.x + bfh(u.z) * qhi.y;
        p += bfl(u.w) * qhi.z + bfh(u.w) * qhi.w;
      }
#pragma unroll
      for (int i4 = 0; i4 < 4; ++i4) {
        const float4 q = qk4[i4];
        p += te[i4*4+0]*q.x + te[i4*4+1]*q.y + te[i4*4+2]*q.z + te[i4*4+3]*q.w;
      }
    }
    p += __shfl_xor(p, 1, 64);
    p += __shfl_xor(p, 2, 64);
    if (my_c == 0) s_s[my_k] = p;
    asm volatile("s_waitcnt lgkmcnt(0)" ::: "memory");

    // ---- softmax (per-lane, reading broadcast s) ----
    float sv[16];
    {
      const float4* s4 = (const float4*)s_s;
#pragma unroll
      for (int i4 = 0; i4 < 4; ++i4) {
        const float4 v = s4[i4];
        sv[i4*4+0]=v.x; sv[i4*4+1]=v.y; sv[i4*4+2]=v.z; sv[i4*4+3]=v.w;
      }
    }
    float m = sv[0];
#pragma unroll
    for (int k = 1; k < 16; ++k) m = fmaxf(m, sv[k]);
    float a[16], sum = 0.f;
#pragma unroll
    for (int k = 0; k < 16; ++k) { a[k] = __expf(sv[k] - m); sum += a[k]; }
    const float inv = 1.f / sum;
#pragma unroll
    for (int k = 0; k < 16; ++k) a[k] *= inv;

    // ---- tagg[j=lane] = sum_k a_k te[k][j]  -> bf16 global ----
    {
      float ta = 0.f;
#pragma unroll
      for (int k = 0; k < 16; ++k) ta += a[k] * te_s[lane * 17 + k];
      tagg[(size_t)n * 128 + lane] = f2bf(ta);
    }

    // ---- partial[h=2*lane, 2*lane+1] = sum_k a_k vo[idx_k][h] ----
    {
      float acc0 = 0.f, acc1 = 0.f;
#pragma unroll
      for (int k = 0; k < 16; ++k) {
        const unsigned int u = vg[k];
        acc0 += a[k] * bfl(u);
        acc1 += a[k] * bfh(u);
      }
      float2 o; o.x = acc0; o.y = acc1;
      ((float2*)(partial + (size_t)n * 128))[lane] = o;
    }
  }
}

// ---------------- out: relu(partial + tagg@Wvo_bot + bo) via MFMA ----------------
__global__ __launch_bounds__(256) void tgat_out(
    const float* __restrict__ bo, float* ws, float* __restrict__ out) {
  const int lane = threadIdx.x & 63, wv = threadIdx.x >> 6;
  const int mr = blockIdx.x * 64 + wv * 16;
  const unsigned short* tagg = (const unsigned short*)(ws + QKX);
  const unsigned short* wvt = (const unsigned short*)(ws + UBASE) + WVOBT;
  const float* partial = ws + QX;
  const int arow = lane & 15, ko = (lane >> 4) * 8;

  bf16x8 af[2];
#pragma unroll
  for (int s = 0; s < 2; ++s)
    af[s] = *(const bf16x8*)(tagg + (size_t)(mr + arow) * 128 + s * 32 + ko);

#pragma unroll
  for (int ct = 0; ct < 8; ++ct) {
    const int col = ct * 16 + arow;
    bf16x8 bf[2];
#pragma unroll
    for (int s = 0; s < 2; ++s)
      bf[s] = *(const bf16x8*)(wvt + (size_t)col * 64 + s * 32 + ko);
    f32x4 acc = {0.f, 0.f, 0.f, 0.f};
    acc = __builtin_amdgcn_mfma_f32_16x16x32_bf16(af[0], bf[0], acc, 0, 0, 0);
    acc = __builtin_amdgcn_mfma_f32_16x16x32_bf16(af[1], bf[1], acc, 0, 0, 0);
    const float bov = bo[col];
#pragma unroll
    for (int r = 0; r < 4; ++r) {
      const int row = mr + (lane >> 4) * 4 + r;
      if (row < NN)
        out[(size_t)row * 128 + col] =
            fmaxf(partial[(size_t)row * 128 + col] + acc[r] + bov, 0.f);
    }
  }
}

extern "C" void kernel_launch(void* const* d_in, const int* in_sizes, int n_in,
                              void* d_out, int out_size, void* d_ws, size_t ws_size,
                              hipStream_t stream) {
  const float* x    = (const float*)d_in[0];
  const float* ts   = (const float*)d_in[1];
  const int*   idx  = (const int*)  d_in[2];
  const float* w0   = (const float*)d_in[3];
  const float* b0   = (const float*)d_in[4];
  const float* t2vW = (const float*)d_in[5];
  const float* t2vB = (const float*)d_in[6];
  const float* Wq   = (const float*)d_in[7];
  const float* Wk   = (const float*)d_in[8];
  const float* Wv   = (const float*)d_in[9];
  const float* Wo   = (const float*)d_in[10];
  const float* bo   = (const float*)d_in[11];
  float* ws = (float*)d_ws;                      // ~77 MB used
  unsigned short* ub = (unsigned short*)(ws + UBASE);
  float* out = (float*)d_out;

  tgat_xcast<<<6250, 256, 0, stream>>>(x, ub + XB);
  tgat_prep<<<321, 128, 0, stream>>>(Wq, Wk, Wv, Wo, b0, t2vB, ws);
  tgat_prep2<<<578, 128, 0, stream>>>(Wq, Wk, w0, b0, t2vW, t2vB, ws, ub);
  tgat_precomp_mfma<<<dim3(3125, 7), 64, 0, stream>>>(ub, ws);
  tgat_main<<<3125, 256, 0, stream>>>(ts, idx, ws);
  tgat_out<<<782, 256, 0, stream>>>(bo, ws, out);
}

// Round 7
// 230.524 us; speedup vs baseline: 38.6290x; 1.2908x over previous
//
#include <hip/hip_runtime.h>
#include <math.h>

#define NN 50000
#define SCL 0.08838834764831845f   // 1/sqrt(128)

// ---- ws layout (float offsets) ----
#define QX    0          // [50000*128] q table; overwritten by `partial` in main
#define QKX   6400000    // [50000*64]  qk table; overwritten by bf16 tagg in main
#define WVOT  9600000    // [128*128]   Wv_top@Wo
#define WVOB  9616384    // [64*128]    Wv_bot@Wo (f32)
#define QC    9624576    // [128]       time2vec(0)@Wq_bot
#define MQK   9624704    // [128*64]    SCL * Wq_top @ Wk_bot^T
#define CQK   9632896    // [64]        SCL * Wk_bot @ qconst
#define WT    9632960    // [64]        [w0, W...]
#define BT    9633024    // [64]        [b0, B...]
#define UBASE 9633088    // ushort region base (16B aligned)
// ushort offsets within ub
#define KXB   0          // [50000*128] bf16 x@Wk_top
#define VOB   6400000    // [50000*128] bf16 x@(Wv_top@Wo)
#define XB    12800000   // [50000*128] bf16 x
#define WCAT  19200000   // [448][128]  bf16 weights [col][k]
#define WVOBT 19257344   // [128][64]   bf16 Wvo_bot^T [h][j]

typedef __attribute__((ext_vector_type(8))) short bf16x8;
typedef __attribute__((ext_vector_type(4))) float f32x4;

__device__ __forceinline__ float bfl(unsigned int u) {   // low bf16 -> f32
  union { unsigned int i; float f; } v; v.i = u << 16; return v.f;
}
__device__ __forceinline__ float bfh(unsigned int u) {   // high bf16 -> f32
  union { unsigned int i; float f; } v; v.i = u & 0xffff0000u; return v.f;
}
__device__ __forceinline__ unsigned short f2bf(float f) {
  union { float f; unsigned int i; } v; v.f = f;
  return (unsigned short)((v.i + 0x7fff + ((v.i >> 16) & 1)) >> 16);  // RNE
}

// ---------------- prep1: folded-weight mini-GEMMs ----------------
__global__ __launch_bounds__(128) void tgat_prep(
    const float* __restrict__ Wq, const float* __restrict__ Wk,
    const float* __restrict__ Wv, const float* __restrict__ Wo,
    const float* __restrict__ t2v_b0, const float* __restrict__ t2v_B,
    float* __restrict__ ws) {
  const int h = threadIdx.x;
  const int b = blockIdx.x;
  if (b < 192) {
    const float* wvrow = Wv + b * 128;
    float acc = 0.f;
#pragma unroll 8
    for (int f = 0; f < 128; ++f) acc += wvrow[f] * Wo[f * 128 + h];
    if (b < 128) ws[WVOT + b * 128 + h] = acc;
    else         ws[WVOB + (b - 128) * 128 + h] = acc;
  } else if (b == 192) {
    float acc = t2v_b0[0] * Wq[128 * 128 + h];
    for (int j = 1; j < 64; ++j)
      acc += __sinf(t2v_B[j - 1]) * Wq[(128 + j) * 128 + h];
    ws[QC + h] = acc;
  } else {
    const int f = b - 193;
    if (h < 64) {
      const float* wqrow = Wq + f * 128;
      const float* wkrow = Wk + (128 + h) * 128;
      float acc = 0.f;
#pragma unroll 8
      for (int i = 0; i < 128; ++i) acc += wqrow[i] * wkrow[i];
      ws[MQK + f * 64 + h] = SCL * acc;
    }
  }
}

// ---------------- prep2 + xcast fused ----------------
__global__ __launch_bounds__(128) void tgat_prep2(
    const float* __restrict__ x, const float* __restrict__ Wq,
    const float* __restrict__ Wk,
    const float* __restrict__ t2v_w0, const float* __restrict__ t2v_b0,
    const float* __restrict__ t2v_W, const float* __restrict__ t2v_B,
    float* __restrict__ ws, unsigned short* __restrict__ ub) {
  const int t = threadIdx.x, b = blockIdx.x;
  if (b >= 578) {                       // xcast: 12500 blocks, 1 float4/thread
    const int i = (b - 578) * 128 + t;
    const float4 v = ((const float4*)x)[i];
    union { unsigned short u[4]; unsigned long long ll; } o;
    o.u[0] = f2bf(v.x); o.u[1] = f2bf(v.y); o.u[2] = f2bf(v.z); o.u[3] = f2bf(v.w);
    ((unsigned long long*)(ub + XB))[i] = o.ll;
    return;
  }
  if (b < 448) {
    float v;
    if (b < 128)      v = Wq[t * 128 + b];
    else if (b < 256) v = Wk[t * 128 + (b - 128)];
    else if (b < 384) v = ws[WVOT + t * 128 + (b - 256)];
    else              v = ws[MQK + t * 64 + (b - 384)];
    ub[WCAT + b * 128 + t] = f2bf(v);
  } else if (b == 448) {
    if (t < 64) {
      const float* wkrow = Wk + (128 + t) * 128;
      float acc = 0.f;
#pragma unroll 8
      for (int i = 0; i < 128; ++i) acc += ws[QC + i] * wkrow[i];
      ws[CQK + t] = SCL * acc;
    }
  } else if (b == 449) {
    if (t < 64) {
      ws[WT + t] = (t == 0) ? t2v_w0[0] : t2v_W[t - 1];
      ws[BT + t] = (t == 0) ? t2v_b0[0] : t2v_B[t - 1];
    }
  } else {
    const int h = b - 450;           // 0..127
    if (t < 64) ub[WVOBT + h * 64 + t] = f2bf(ws[WVOB + t * 128 + h]);
  }
}

// ---------------- precomp: [50000,128]@[128,448]; 1 wave = 16 rows x 448 cols ----------------
__global__ __launch_bounds__(64) void tgat_precomp_mfma(
    const unsigned short* __restrict__ ub, float* ws) {
  const int lane = threadIdx.x;
  const int mr = blockIdx.x * 16;        // 3125 blocks * 16 = 50000 exactly
  const unsigned short* xb = ub + XB;
  const unsigned short* wc = ub + WCAT;
  const int arow = lane & 15;
  const int ko = (lane >> 4) * 8;
  const int rbase = (lane >> 4) * 4;

  bf16x8 afr[4];
#pragma unroll
  for (int kk = 0; kk < 4; ++kk)
    afr[kk] = *(const bf16x8*)(xb + (size_t)(mr + arow) * 128 + kk * 32 + ko);

  unsigned short* kxb = (unsigned short*)(ws + UBASE) + KXB;
  unsigned short* vob = (unsigned short*)(ws + UBASE) + VOB;

#pragma unroll 4
  for (int ct = 0; ct < 28; ++ct) {
    const int col = ct * 16 + arow;
    bf16x8 bfr[4];
#pragma unroll
    for (int kk = 0; kk < 4; ++kk)
      bfr[kk] = *(const bf16x8*)(wc + (size_t)col * 128 + kk * 32 + ko);
    f32x4 acc = {0.f, 0.f, 0.f, 0.f};
#pragma unroll
    for (int kk = 0; kk < 4; ++kk)
      acc = __builtin_amdgcn_mfma_f32_16x16x32_bf16(afr[kk], bfr[kk], acc, 0, 0, 0);

    const int gc = ct * 16 + arow;       // output column for stores (cl == arow)
    if (ct < 8) {
      const float qc = ws[QC + gc];
#pragma unroll
      for (int r = 0; r < 4; ++r)
        ws[QX + (size_t)(mr + rbase + r) * 128 + gc] = (acc[r] + qc) * SCL;
    } else if (ct < 16) {
#pragma unroll
      for (int r = 0; r < 4; ++r)
        kxb[(size_t)(mr + rbase + r) * 128 + (gc - 128)] = f2bf(acc[r]);
    } else if (ct < 24) {
#pragma unroll
      for (int r = 0; r < 4; ++r)
        vob[(size_t)(mr + rbase + r) * 128 + (gc - 256)] = f2bf(acc[r]);
    } else {
      const float cq = ws[CQK + gc - 384];
#pragma unroll
      for (int r = 0; r < 4; ++r)
        ws[QKX + (size_t)(mr + rbase + r) * 64 + (gc - 384)] = acc[r] + cq;
    }
  }
}

// ---------------- main: one wave per node; LDS-staged q/qk; deep prefetch ----------------
__global__ __launch_bounds__(256, 4) void tgat_main(
    const float* __restrict__ ts, const int* __restrict__ idx,
    float* ws) {
  const int lane = threadIdx.x & 63;
  const int wv   = threadIdx.x >> 6;
  const int my_k = lane >> 2, my_c = lane & 3;

  __shared__ float lds[4 * 1312];
  float* te_s = lds + wv * 1312;        // [64 j][17] (col = k, pad)
  float* s_s  = te_s + 1088;            // [16]
  float* q_s  = te_s + 1104;            // [4 blocks][36] (stride-36 => conflict-free f4)
  float* qk_s = te_s + 1248;            // [64]

  const float* qx  = ws + QX;
  const float* qkx = ws + QKX;
  const unsigned short* kxb = (const unsigned short*)(ws + UBASE) + KXB;
  const unsigned short* vob = (const unsigned short*)(ws + UBASE) + VOB;
  float* partial = ws + QX;                              // overlay (same row, after read)
  unsigned short* tagg = (unsigned short*)(ws + QKX);    // overlay (same row, after read)

  const int n = blockIdx.x * 4 + wv;     // 12500 * 4 = 50000 exactly

  // ---- issue all memory up front ----
  const int   iv = idx[n * 16 + (lane & 15)];
  const float tv = ts[n * 16 + (lane & 15)];
  const float2 qv = ((const float2*)(qx + (size_t)n * 128))[lane];
  const float qkv = qkx[(size_t)n * 64 + lane];

  const int i_myk = __shfl(iv, my_k, 64);
  const unsigned short* kr = kxb + (size_t)i_myk * 128 + my_c * 32;
  const uint4 kx0 = *(const uint4*)(kr);
  const uint4 kx1 = *(const uint4*)(kr + 8);
  const uint4 kx2 = *(const uint4*)(kr + 16);
  const uint4 kx3 = *(const uint4*)(kr + 24);
  unsigned int vg[16];
#pragma unroll
  for (int k = 0; k < 16; ++k) {
    const int ik = __shfl(iv, k, 64);
    vg[k] = ((const unsigned int*)(vob + (size_t)ik * 128))[lane];
  }

  // ---- time2vec (coeffs loaded transiently; L2-hot) ----
  const float tvk = __shfl(tv, my_k, 64);
  float te[16];
  {
    const float4* w4 = (const float4*)(ws + WT + my_c * 16);
    const float4* b4 = (const float4*)(ws + BT + my_c * 16);
#pragma unroll
    for (int i4 = 0; i4 < 4; ++i4) {
      const float4 a = w4[i4], b = b4[i4];
      te[i4*4+0] = __sinf(tvk * a.x + b.x);
      te[i4*4+1] = __sinf(tvk * a.y + b.y);
      te[i4*4+2] = __sinf(tvk * a.z + b.z);
      te[i4*4+3] = __sinf(tvk * a.w + b.w);
    }
  }
  if (my_c == 0) te[0] = tvk * (ws[WT]) + ws[BT];   // j==0 linear term (scalar, L2)

  // ---- stage q/qk/te into wave-private LDS ----
  {
    const int f = 2 * lane;
    const int qi = (f >> 5) * 36 + (f & 31);
    q_s[qi] = qv.x; q_s[qi + 1] = qv.y;
  }
  qk_s[lane] = qkv;
#pragma unroll
  for (int i = 0; i < 16; ++i)
    te_s[(my_c * 16 + i) * 17 + my_k] = te[i];
  asm volatile("s_waitcnt lgkmcnt(0)" ::: "memory");

  // ---- score: s_k = q . kx[idx_k] (32 feats/lane) + te . qk (16 feats/lane) ----
  float p = 0.f;
  {
    const float4* qb = (const float4*)(q_s + my_c * 36);
#pragma unroll
    for (int q8 = 0; q8 < 4; ++q8) {
      const uint4 u = (q8 == 0) ? kx0 : (q8 == 1) ? kx1 : (q8 == 2) ? kx2 : kx3;
      const float4 qlo = qb[q8 * 2], qhi = qb[q8 * 2 + 1];
      p += bfl(u.x) * qlo.x + bfh(u.x) * qlo.y;
      p += bfl(u.y) * qlo.z + bfh(u.y) * qlo.w;
      p += bfl(u.z) * qhi.x + bfh(u.z) * qhi.y;
      p += bfl(u.w) * qhi.z + bfh(u.w) * qhi.w;
    }
    const float4* qq4 = (const float4*)(qk_s + my_c * 16);
#pragma unroll
    for (int i4 = 0; i4 < 4; ++i4) {
      const float4 q = qq4[i4];
      p += te[i4*4+0]*q.x + te[i4*4+1]*q.y + te[i4*4+2]*q.z + te[i4*4+3]*q.w;
    }
  }
  p += __shfl_xor(p, 1, 64);
  p += __shfl_xor(p, 2, 64);
  if (my_c == 0) s_s[my_k] = p;
  asm volatile("s_waitcnt lgkmcnt(0)" ::: "memory");

  // ---- softmax over 16 (redundant per lane; broadcast reads) ----
  float a[16];
  {
    float sv[16];
    const float4* s4 = (const float4*)s_s;
#pragma unroll
    for (int i4 = 0; i4 < 4; ++i4) {
      const float4 v = s4[i4];
      sv[i4*4+0]=v.x; sv[i4*4+1]=v.y; sv[i4*4+2]=v.z; sv[i4*4+3]=v.w;
    }
    float m = sv[0];
#pragma unroll
    for (int k = 1; k < 16; ++k) m = fmaxf(m, sv[k]);
    float sum = 0.f;
#pragma unroll
    for (int k = 0; k < 16; ++k) { a[k] = __expf(sv[k] - m); sum += a[k]; }
    const float inv = 1.f / sum;
#pragma unroll
    for (int k = 0; k < 16; ++k) a[k] *= inv;
  }

  // ---- tagg[j=lane] = sum_k a_k te[k][j] -> bf16 global ----
  {
    float ta = 0.f;
#pragma unroll
    for (int k = 0; k < 16; ++k) ta += a[k] * te_s[lane * 17 + k];
    tagg[(size_t)n * 128 + lane] = f2bf(ta);
  }

  // ---- partial[h=2*lane, 2*lane+1] = sum_k a_k vo[idx_k][h] ----
  {
    float acc0 = 0.f, acc1 = 0.f;
#pragma unroll
    for (int k = 0; k < 16; ++k) {
      const unsigned int u = vg[k];
      acc0 += a[k] * bfl(u);
      acc1 += a[k] * bfh(u);
    }
    float2 o; o.x = acc0; o.y = acc1;
    ((float2*)(partial + (size_t)n * 128))[lane] = o;
  }
}

// ---------------- out: relu(partial + tagg@Wvo_bot + bo) via MFMA ----------------
__global__ __launch_bounds__(256) void tgat_out(
    const float* __restrict__ bo, float* ws, float* __restrict__ out) {
  const int lane = threadIdx.x & 63, wv = threadIdx.x >> 6;
  const int mr = blockIdx.x * 64 + wv * 16;
  const unsigned short* tagg = (const unsigned short*)(ws + QKX);
  const unsigned short* wvt = (const unsigned short*)(ws + UBASE) + WVOBT;
  const float* partial = ws + QX;
  const int arow = lane & 15, ko = (lane >> 4) * 8;

  bf16x8 af[2];
#pragma unroll
  for (int s = 0; s < 2; ++s)
    af[s] = *(const bf16x8*)(tagg + (size_t)(mr + arow) * 128 + s * 32 + ko);

#pragma unroll
  for (int ct = 0; ct < 8; ++ct) {
    const int col = ct * 16 + arow;
    bf16x8 bf[2];
#pragma unroll
    for (int s = 0; s < 2; ++s)
      bf[s] = *(const bf16x8*)(wvt + (size_t)col * 64 + s * 32 + ko);
    f32x4 acc = {0.f, 0.f, 0.f, 0.f};
    acc = __builtin_amdgcn_mfma_f32_16x16x32_bf16(af[0], bf[0], acc, 0, 0, 0);
    acc = __builtin_amdgcn_mfma_f32_16x16x32_bf16(af[1], bf[1], acc, 0, 0, 0);
    const float bov = bo[col];
#pragma unroll
    for (int r = 0; r < 4; ++r) {
      const int row = mr + (lane >> 4) * 4 + r;
      if (row < NN)
        out[(size_t)row * 128 + col] =
            fmaxf(partial[(size_t)row * 128 + col] + acc[r] + bov, 0.f);
    }
  }
}

extern "C" void kernel_launch(void* const* d_in, const int* in_sizes, int n_in,
                              void* d_out, int out_size, void* d_ws, size_t ws_size,
                              hipStream_t stream) {
  const float* x    = (const float*)d_in[0];
  const float* ts   = (const float*)d_in[1];
  const int*   idx  = (const int*)  d_in[2];
  const float* w0   = (const float*)d_in[3];
  const float* b0   = (const float*)d_in[4];
  const float* t2vW = (const float*)d_in[5];
  const float* t2vB = (const float*)d_in[6];
  const float* Wq   = (const float*)d_in[7];
  const float* Wk   = (const float*)d_in[8];
  const float* Wv   = (const float*)d_in[9];
  const float* Wo   = (const float*)d_in[10];
  const float* bo   = (const float*)d_in[11];
  float* ws = (float*)d_ws;                      // ~77 MB used
  unsigned short* ub = (unsigned short*)(ws + UBASE);
  float* out = (float*)d_out;

  tgat_prep<<<321, 128, 0, stream>>>(Wq, Wk, Wv, Wo, b0, t2vB, ws);
  tgat_prep2<<<13078, 128, 0, stream>>>(x, Wq, Wk, w0, b0, t2vW, t2vB, ws, ub);
  tgat_precomp_mfma<<<3125, 64, 0, stream>>>(ub, ws);
  tgat_main<<<12500, 256, 0, stream>>>(ts, idx, ws);
  tgat_out<<<782, 256, 0, stream>>>(bo, ws, out);
}

// Round 8
// 218.780 us; speedup vs baseline: 40.7026x; 1.0537x over previous
//
#include <hip/hip_runtime.h>
#include <math.h>

#define NN 50000
#define SCL 0.08838834764831845f   // 1/sqrt(128)

// ---- ws layout (float offsets) ----
#define QX    0          // [50000*128] f32 q table
#define QKX   6400000    // [50000*64]  f32 qk table
#define WVOT  9600000    // [128*128]   Wv_top@Wo
#define WVOB  9616384    // [64*128]    Wv_bot@Wo (f32)
#define QC    9624576    // [128]       time2vec(0)@Wq_bot
#define MQK   9624704    // [128*64]    SCL * Wq_top @ Wk_bot^T
#define CQK   9632896    // [64]        SCL * Wk_bot @ qconst
#define WT    9632960    // [64]        [w0, W...]
#define BT    9633024    // [64]        [b0, B...]
#define UBASE 9633088    // ushort region base (16B aligned)
// ushort offsets within ub
#define KXB   0          // [50000*128] bf16 x@Wk_top
#define VOB   6400000    // [50000*128] bf16 x@(Wv_top@Wo)
#define WCAT  12800000   // [448][128]  bf16 weights [col][k]
#define WVOP  12857344   // [64][64]    u32-packed bf16 (wvo[j][2hp], wvo[j][2hp+1])

typedef __attribute__((ext_vector_type(8))) short bf16x8;
typedef __attribute__((ext_vector_type(4))) float f32x4;

__device__ __forceinline__ float bfl(unsigned int u) {   // low bf16 -> f32
  union { unsigned int i; float f; } v; v.i = u << 16; return v.f;
}
__device__ __forceinline__ float bfh(unsigned int u) {   // high bf16 -> f32
  union { unsigned int i; float f; } v; v.i = u & 0xffff0000u; return v.f;
}
__device__ __forceinline__ unsigned short f2bf(float f) {
  union { float f; unsigned int i; } v; v.f = f;
  return (unsigned short)((v.i + 0x7fff + ((v.i >> 16) & 1)) >> 16);  // RNE
}

// ---------------- prep1: folded-weight mini-GEMMs ----------------
__global__ __launch_bounds__(128) void tgat_prep(
    const float* __restrict__ Wq, const float* __restrict__ Wk,
    const float* __restrict__ Wv, const float* __restrict__ Wo,
    const float* __restrict__ t2v_b0, const float* __restrict__ t2v_B,
    float* __restrict__ ws) {
  const int h = threadIdx.x;
  const int b = blockIdx.x;
  if (b < 192) {
    const float* wvrow = Wv + b * 128;
    float acc = 0.f;
#pragma unroll 8
    for (int f = 0; f < 128; ++f) acc += wvrow[f] * Wo[f * 128 + h];
    if (b < 128) ws[WVOT + b * 128 + h] = acc;
    else         ws[WVOB + (b - 128) * 128 + h] = acc;
  } else if (b == 192) {
    float acc = t2v_b0[0] * Wq[128 * 128 + h];
    for (int j = 1; j < 64; ++j)
      acc += __sinf(t2v_B[j - 1]) * Wq[(128 + j) * 128 + h];
    ws[QC + h] = acc;
  } else {
    const int f = b - 193;
    if (h < 64) {
      const float* wqrow = Wq + f * 128;
      const float* wkrow = Wk + (128 + h) * 128;
      float acc = 0.f;
#pragma unroll 8
      for (int i = 0; i < 128; ++i) acc += wqrow[i] * wkrow[i];
      ws[MQK + f * 64 + h] = SCL * acc;
    }
  }
}

// ---------------- prep2: WCAT, cqk, wt/bt, packed Wvo_bot ----------------
__global__ __launch_bounds__(128) void tgat_prep2(
    const float* __restrict__ Wq, const float* __restrict__ Wk,
    const float* __restrict__ t2v_w0, const float* __restrict__ t2v_b0,
    const float* __restrict__ t2v_W, const float* __restrict__ t2v_B,
    float* __restrict__ ws, unsigned short* __restrict__ ub) {
  const int t = threadIdx.x, b = blockIdx.x;
  if (b < 448) {
    float v;
    if (b < 128)      v = Wq[t * 128 + b];
    else if (b < 256) v = Wk[t * 128 + (b - 128)];
    else if (b < 384) v = ws[WVOT + t * 128 + (b - 256)];
    else              v = ws[MQK + t * 64 + (b - 384)];
    ub[WCAT + b * 128 + t] = f2bf(v);
  } else if (b == 448) {
    if (t < 64) {
      const float* wkrow = Wk + (128 + t) * 128;
      float acc = 0.f;
#pragma unroll 8
      for (int i = 0; i < 128; ++i) acc += ws[QC + i] * wkrow[i];
      ws[CQK + t] = SCL * acc;
    }
  } else if (b == 449) {
    if (t < 64) {
      ws[WT + t] = (t == 0) ? t2v_w0[0] : t2v_W[t - 1];
      ws[BT + t] = (t == 0) ? t2v_b0[0] : t2v_B[t - 1];
    }
  } else {
    const int j = b - 450;            // 0..63
    if (t < 64) {
      const float lo = ws[WVOB + j * 128 + 2 * t];
      const float hi = ws[WVOB + j * 128 + 2 * t + 1];
      unsigned* wp = (unsigned*)(ub + WVOP);
      wp[j * 64 + t] = (unsigned)f2bf(lo) | ((unsigned)f2bf(hi) << 16);
    }
  }
}

// ---------------- precomp: [50000,128]@[128,448]; reads x f32, casts in-reg ----------------
__global__ __launch_bounds__(64) void tgat_precomp_mfma(
    const float* __restrict__ x, const unsigned short* __restrict__ ub,
    float* ws) {
  const int lane = threadIdx.x;
  const int mr = blockIdx.x * 16;        // 3125 blocks * 16 = 50000 exactly
  const unsigned short* wc = ub + WCAT;
  const int arow = lane & 15;
  const int ko = (lane >> 4) * 8;
  const int rbase = (lane >> 4) * 4;

  // A fragments: load f32, round to bf16 in registers
  bf16x8 afr[4];
  {
    const float* xrow = x + (size_t)(mr + arow) * 128;
#pragma unroll
    for (int kk = 0; kk < 4; ++kk) {
      const float4 lo = *(const float4*)(xrow + kk * 32 + ko);
      const float4 hi = *(const float4*)(xrow + kk * 32 + ko + 4);
      bf16x8 f;
      f[0] = (short)f2bf(lo.x); f[1] = (short)f2bf(lo.y);
      f[2] = (short)f2bf(lo.z); f[3] = (short)f2bf(lo.w);
      f[4] = (short)f2bf(hi.x); f[5] = (short)f2bf(hi.y);
      f[6] = (short)f2bf(hi.z); f[7] = (short)f2bf(hi.w);
      afr[kk] = f;
    }
  }

  unsigned short* kxb = (unsigned short*)(ws + UBASE) + KXB;
  unsigned short* vob = (unsigned short*)(ws + UBASE) + VOB;

#pragma unroll 4
  for (int ct = 0; ct < 28; ++ct) {
    const int col = ct * 16 + arow;
    bf16x8 bfr[4];
#pragma unroll
    for (int kk = 0; kk < 4; ++kk)
      bfr[kk] = *(const bf16x8*)(wc + (size_t)col * 128 + kk * 32 + ko);
    f32x4 acc = {0.f, 0.f, 0.f, 0.f};
#pragma unroll
    for (int kk = 0; kk < 4; ++kk)
      acc = __builtin_amdgcn_mfma_f32_16x16x32_bf16(afr[kk], bfr[kk], acc, 0, 0, 0);

    const int gc = ct * 16 + arow;       // output column (cl == arow)
    if (ct < 8) {
      const float qc = ws[QC + gc];
#pragma unroll
      for (int r = 0; r < 4; ++r)
        ws[QX + (size_t)(mr + rbase + r) * 128 + gc] = (acc[r] + qc) * SCL;
    } else if (ct < 16) {
#pragma unroll
      for (int r = 0; r < 4; ++r)
        kxb[(size_t)(mr + rbase + r) * 128 + (gc - 128)] = f2bf(acc[r]);
    } else if (ct < 24) {
#pragma unroll
      for (int r = 0; r < 4; ++r)
        vob[(size_t)(mr + rbase + r) * 128 + (gc - 256)] = f2bf(acc[r]);
    } else {
      const float cq = ws[CQK + gc - 384];
#pragma unroll
      for (int r = 0; r < 4; ++r)
        ws[QKX + (size_t)(mr + rbase + r) * 64 + (gc - 384)] = acc[r] + cq;
    }
  }
}

// ---------------- main: one wave per node; fused output GEMV + relu ----------------
__global__ __launch_bounds__(256, 4) void tgat_main(
    const float* __restrict__ ts, const int* __restrict__ idx,
    const float* __restrict__ bo, const float* __restrict__ ws,
    float* __restrict__ out) {
  const int lane = threadIdx.x & 63;
  const int wv   = threadIdx.x >> 6;
  const int my_k = lane >> 2, my_c = lane & 3;

  __shared__ float lds[4 * 1312];
  __shared__ unsigned wvo_l[4096];      // [j][hp] packed bf16 pairs, 16 KB
  float* te_s = lds + wv * 1312;        // [64 j][17] (col = k, pad)
  float* s_s  = te_s + 1088;            // [16]
  float* q_s  = te_s + 1104;            // [4 blocks][36] (stride-36 => conflict-free f4)
  float* qk_s = te_s + 1248;            // [64]; reused for tagg after score

  const float* qx  = ws + QX;
  const float* qkx = ws + QKX;
  const unsigned short* ubr = (const unsigned short*)(ws + UBASE);
  const unsigned short* kxb = ubr + KXB;
  const unsigned short* vob = ubr + VOB;

  const int n = blockIdx.x * 4 + wv;     // 12500 * 4 = 50000 exactly

  // ---- stage packed Wvo_bot into LDS (block-shared; barrier later) ----
  {
    const uint4* wvp = (const uint4*)(ubr + WVOP);
#pragma unroll
    for (int i = 0; i < 4; ++i)
      ((uint4*)wvo_l)[threadIdx.x + i * 256] = wvp[threadIdx.x + i * 256];
  }

  // ---- issue all per-node memory up front ----
  const int   iv = idx[n * 16 + (lane & 15)];
  const float tv = ts[n * 16 + (lane & 15)];
  const float2 qv = ((const float2*)(qx + (size_t)n * 128))[lane];
  const float qkv = qkx[(size_t)n * 64 + lane];
  const float2 bo2 = ((const float2*)bo)[lane];

  const int i_myk = __shfl(iv, my_k, 64);
  const unsigned short* kr = kxb + (size_t)i_myk * 128 + my_c * 32;
  const uint4 kx0 = *(const uint4*)(kr);
  const uint4 kx1 = *(const uint4*)(kr + 8);
  const uint4 kx2 = *(const uint4*)(kr + 16);
  const uint4 kx3 = *(const uint4*)(kr + 24);
  unsigned int vg[16];
#pragma unroll
  for (int k = 0; k < 16; ++k) {
    const int ik = __shfl(iv, k, 64);
    vg[k] = ((const unsigned int*)(vob + (size_t)ik * 128))[lane];
  }

  // ---- time2vec (coeffs transient; L2-hot) ----
  const float tvk = __shfl(tv, my_k, 64);
  float te[16];
  {
    const float4* w4 = (const float4*)(ws + WT + my_c * 16);
    const float4* b4 = (const float4*)(ws + BT + my_c * 16);
#pragma unroll
    for (int i4 = 0; i4 < 4; ++i4) {
      const float4 a = w4[i4], b = b4[i4];
      te[i4*4+0] = __sinf(tvk * a.x + b.x);
      te[i4*4+1] = __sinf(tvk * a.y + b.y);
      te[i4*4+2] = __sinf(tvk * a.z + b.z);
      te[i4*4+3] = __sinf(tvk * a.w + b.w);
    }
  }
  if (my_c == 0) te[0] = tvk * (ws[WT]) + ws[BT];   // j==0 linear term

  // ---- stage q/qk/te into wave-private LDS ----
  {
    const int f = 2 * lane;
    const int qi = (f >> 5) * 36 + (f & 31);
    q_s[qi] = qv.x; q_s[qi + 1] = qv.y;
  }
  qk_s[lane] = qkv;
#pragma unroll
  for (int i = 0; i < 16; ++i)
    te_s[(my_c * 16 + i) * 17 + my_k] = te[i];
  asm volatile("s_waitcnt lgkmcnt(0)" ::: "memory");

  // ---- score: s_k = q . kx[idx_k] (32 feats/lane) + te . qk (16 feats/lane) ----
  float p = 0.f;
  {
    const float4* qb = (const float4*)(q_s + my_c * 36);
#pragma unroll
    for (int q8 = 0; q8 < 4; ++q8) {
      const uint4 u = (q8 == 0) ? kx0 : (q8 == 1) ? kx1 : (q8 == 2) ? kx2 : kx3;
      const float4 qlo = qb[q8 * 2], qhi = qb[q8 * 2 + 1];
      p += bfl(u.x) * qlo.x + bfh(u.x) * qlo.y;
      p += bfl(u.y) * qlo.z + bfh(u.y) * qlo.w;
      p += bfl(u.z) * qhi.x + bfh(u.z) * qhi.y;
      p += bfl(u.w) * qhi.z + bfh(u.w) * qhi.w;
    }
    const float4* qq4 = (const float4*)(qk_s + my_c * 16);
#pragma unroll
    for (int i4 = 0; i4 < 4; ++i4) {
      const float4 q = qq4[i4];
      p += te[i4*4+0]*q.x + te[i4*4+1]*q.y + te[i4*4+2]*q.z + te[i4*4+3]*q.w;
    }
  }
  p += __shfl_xor(p, 1, 64);
  p += __shfl_xor(p, 2, 64);
  if (my_c == 0) s_s[my_k] = p;
  asm volatile("s_waitcnt lgkmcnt(0)" ::: "memory");

  // ---- softmax over 16 (redundant per lane; broadcast reads) ----
  float a[16];
  {
    float sv[16];
    const float4* s4 = (const float4*)s_s;
#pragma unroll
    for (int i4 = 0; i4 < 4; ++i4) {
      const float4 v = s4[i4];
      sv[i4*4+0]=v.x; sv[i4*4+1]=v.y; sv[i4*4+2]=v.z; sv[i4*4+3]=v.w;
    }
    float m = sv[0];
#pragma unroll
    for (int k = 1; k < 16; ++k) m = fmaxf(m, sv[k]);
    float sum = 0.f;
#pragma unroll
    for (int k = 0; k < 16; ++k) { a[k] = __expf(sv[k] - m); sum += a[k]; }
    const float inv = 1.f / sum;
#pragma unroll
    for (int k = 0; k < 16; ++k) a[k] *= inv;
  }

  // ---- tagg[j=lane] = sum_k a_k te[k][j] -> qk_s (wave-private reuse) ----
  {
    float ta = 0.f;
#pragma unroll
    for (int k = 0; k < 16; ++k) ta += a[k] * te_s[lane * 17 + k];
    qk_s[lane] = ta;
  }
  asm volatile("s_waitcnt lgkmcnt(0)" ::: "memory");

  // ---- vo aggregation: acc_h = bo_h + sum_k a_k vo[idx_k][h], h = 2lane,2lane+1 ----
  float acc0 = bo2.x, acc1 = bo2.y;
#pragma unroll
  for (int k = 0; k < 16; ++k) {
    const unsigned int u = vg[k];
    acc0 += a[k] * bfl(u);
    acc1 += a[k] * bfh(u);
  }

  // ---- fused output GEMV: acc += tagg @ Wvo_bot[:, h] (wvo in LDS, bf16 pairs) ----
  __syncthreads();                      // wvo_l ready (single block-wide barrier)
  {
    const float4* ta4 = (const float4*)qk_s;
#pragma unroll
    for (int j4 = 0; j4 < 16; ++j4) {
      const float4 tb = ta4[j4];        // broadcast read
      const unsigned u0 = wvo_l[(j4*4+0) * 64 + lane];
      const unsigned u1 = wvo_l[(j4*4+1) * 64 + lane];
      const unsigned u2 = wvo_l[(j4*4+2) * 64 + lane];
      const unsigned u3 = wvo_l[(j4*4+3) * 64 + lane];
      acc0 += tb.x * bfl(u0); acc1 += tb.x * bfh(u0);
      acc0 += tb.y * bfl(u1); acc1 += tb.y * bfh(u1);
      acc0 += tb.z * bfl(u2); acc1 += tb.z * bfh(u2);
      acc0 += tb.w * bfl(u3); acc1 += tb.w * bfh(u3);
    }
  }

  float2 o; o.x = fmaxf(acc0, 0.f); o.y = fmaxf(acc1, 0.f);
  ((float2*)(out + (size_t)n * 128))[lane] = o;
}

extern "C" void kernel_launch(void* const* d_in, const int* in_sizes, int n_in,
                              void* d_out, int out_size, void* d_ws, size_t ws_size,
                              hipStream_t stream) {
  const float* x    = (const float*)d_in[0];
  const float* ts   = (const float*)d_in[1];
  const int*   idx  = (const int*)  d_in[2];
  const float* w0   = (const float*)d_in[3];
  const float* b0   = (const float*)d_in[4];
  const float* t2vW = (const float*)d_in[5];
  const float* t2vB = (const float*)d_in[6];
  const float* Wq   = (const float*)d_in[7];
  const float* Wk   = (const float*)d_in[8];
  const float* Wv   = (const float*)d_in[9];
  const float* Wo   = (const float*)d_in[10];
  const float* bo   = (const float*)d_in[11];
  float* ws = (float*)d_ws;                      // ~64.3 MB used
  unsigned short* ub = (unsigned short*)(ws + UBASE);
  float* out = (float*)d_out;

  tgat_prep<<<321, 128, 0, stream>>>(Wq, Wk, Wv, Wo, b0, t2vB, ws);
  tgat_prep2<<<514, 128, 0, stream>>>(Wq, Wk, w0, b0, t2vW, t2vB, ws, ub);
  tgat_precomp_mfma<<<3125, 64, 0, stream>>>(x, ub, ws);
  tgat_main<<<12500, 256, 0, stream>>>(ts, idx, bo, ws, out);
}